// Round 7
// baseline (142.779 us; speedup 1.0000x reference)
//
#include <hip/hip_runtime.h>
#include <hip/hip_bf16.h>

typedef __bf16 bf16x8 __attribute__((ext_vector_type(8)));
typedef float  f32x4  __attribute__((ext_vector_type(4)));
typedef float  f32x16 __attribute__((ext_vector_type(16)));
typedef unsigned short u16x8 __attribute__((ext_vector_type(8)));
typedef unsigned short u16x4 __attribute__((ext_vector_type(4)));
typedef unsigned int   u32x4 __attribute__((ext_vector_type(4)));

// ---------- helpers ----------

__device__ __forceinline__ unsigned short f2bf(float f) {
  return __builtin_bit_cast(unsigned short, (__bf16)f);  // RNE via v_cvt
}

__device__ __forceinline__ bf16x8 ld8(const unsigned short* p) {
  return __builtin_bit_cast(bf16x8, *reinterpret_cast<const u16x8*>(p));
}

// packed f32x2 -> bf16x2 (low = a, high = b)
__device__ __forceinline__ unsigned int cvtpk(float a, float b) {
  unsigned int r;
  asm("v_cvt_pk_bf16_f32 %0, %1, %2" : "=v"(r) : "v"(a), "v"(b));
  return r;
}

// async global->LDS, 16B per lane. lds base must be wave-uniform (HW adds lane*16).
__device__ __forceinline__ void gload16(const unsigned short* src, unsigned short* lds) {
  __builtin_amdgcn_global_load_lds(
      (const __attribute__((address_space(1))) unsigned int*)src,
      (__attribute__((address_space(3))) unsigned int*)lds,
      16, 0, 0);
}

// ---------- input conversion: f32 -> bf16 ----------

__global__ __launch_bounds__(256) void cvt_inputs(
    const float* __restrict__ x, const float* __restrict__ Wq,
    const float* __restrict__ Wk, const float* __restrict__ Wv,
    const float* __restrict__ Wo,
    unsigned short* __restrict__ xb, unsigned short* __restrict__ wb) {
  const int NXC = 4194304 / 8;
  const int NWC = 1048576 / 8;   // 131072 = 2^17
  const int total = NXC + 4 * NWC;
  for (int cid = blockIdx.x * 256 + threadIdx.x; cid < total; cid += gridDim.x * 256) {
    const float* s; unsigned short* d; int off;
    if (cid < NXC) { s = x; d = xb; off = cid * 8; }
    else {
      const int c2 = cid - NXC; const int w = c2 >> 17; const int o2 = c2 & (NWC - 1);
      s = (w == 0) ? Wq : (w == 1) ? Wk : (w == 2) ? Wv : Wo;
      d = wb + (size_t)w * 1048576;
      off = o2 * 8;
    }
    const f32x4 a  = *reinterpret_cast<const f32x4*>(s + off);
    const f32x4 b2 = *reinterpret_cast<const f32x4*>(s + off + 4);
    u16x8 o;
#pragma unroll
    for (int j = 0; j < 4; ++j) { o[j] = f2bf(a[j]); o[j + 4] = f2bf(b2[j]); }
    *reinterpret_cast<u16x8*>(d + off) = o;
  }
}

// ---------- GEMM: C[m,n] = sum_k A[m,k] * W[n,k]  (NT, bf16 in, f32 acc) ----------
// BM x 128 tile, BK=32, 256 threads, 2x2 waves (wave m-tile = BM/2 rows).
// FM = (BM/2)/16 = BM/32 m-frags per wave (16 rows each).
// mode 0: C float32 row-major (M x 1024)
// mode 1: C bf16 -> qk layout  [(b*16+h)*2048 + s]*64 + d
// mode 2: C bf16 -> v-transposed [(b*16+h)*64 + d]*2048 + s

template<int BM>
__device__ __forceinline__ void gemm_body(const unsigned short* __restrict__ A,
                                          const unsigned short* __restrict__ W,
                                          void* __restrict__ Cv, int mode) {
  constexpr int FM  = BM / 32;    // m-frags per wave (wave tile BM/2, 16 rows/frag)
  constexpr int WTM = BM / 2;     // wave m-tile
  __shared__ unsigned short As[2][BM * 32];
  __shared__ unsigned short Bs[2][128 * 32];
  const int tid  = threadIdx.x;
  const int lane = tid & 63;
  const int g    = lane >> 4;
  const int lo   = lane & 15;
  const int wid  = tid >> 6;
  const int m0   = blockIdx.y * BM;
  const int n0   = blockIdx.x * 128;
  const int wm   = wid >> 1, wn = wid & 1;

  f32x4 acc[FM][4] = {};

  auto stage = [&](int buf, int k0) {
#pragma unroll
    for (int i = 0; i < BM / 64; ++i) {          // A: BM*4 chunks of 16B
      const int c   = (i * 4 + wid) * 64 + lane;
      const int row = c >> 2, cc = c & 3;        // 4 chunks per 64B row (BK=32)
      gload16(A + (size_t)(m0 + row) * 1024 + k0 + cc * 8, &As[buf][(i * 4 + wid) * 512]);
    }
#pragma unroll
    for (int i = 0; i < 2; ++i) {                // B: 512 chunks
      const int c   = (i * 4 + wid) * 64 + lane;
      const int row = c >> 2, cc = c & 3;
      gload16(W + (size_t)(n0 + row) * 1024 + k0 + cc * 8, &Bs[buf][(i * 4 + wid) * 512]);
    }
  };

  stage(0, 0);
  __syncthreads();
  int cur = 0;
  for (int t = 0; t < 32; ++t) {
    if (t < 31) stage(cur ^ 1, (t + 1) * 32);
    bf16x8 af[FM], bvf[4];
#pragma unroll
    for (int mi = 0; mi < FM; ++mi)
      af[mi] = ld8(&As[cur][(wm * WTM + mi * 16 + lo) * 32 + g * 8]);
#pragma unroll
    for (int ni = 0; ni < 4; ++ni)
      bvf[ni] = ld8(&Bs[cur][(wn * 64 + ni * 16 + lo) * 32 + g * 8]);
#pragma unroll
    for (int mi = 0; mi < FM; ++mi)
#pragma unroll
      for (int ni = 0; ni < 4; ++ni)
        acc[mi][ni] = __builtin_amdgcn_mfma_f32_16x16x32_bf16(af[mi], bvf[ni], acc[mi][ni], 0, 0, 0);
    __syncthreads();
    cur ^= 1;
  }

  // epilogue: C/D layout col = lane&15 (n), row = g*4 + r (m)
#pragma unroll
  for (int mi = 0; mi < FM; ++mi) {
#pragma unroll
    for (int ni = 0; ni < 4; ++ni) {
      const int gcol = n0 + wn * 64 + ni * 16 + lo;
#pragma unroll
      for (int r = 0; r < 4; ++r) {
        const int grow = m0 + wm * WTM + mi * 16 + g * 4 + r;
        if (mode == 0) {
          ((float*)Cv)[(size_t)grow * 1024 + gcol] = acc[mi][ni][r];
        } else {
          const unsigned short bv = f2bf(acc[mi][ni][r]);
          const int b = grow >> 11, s = grow & 2047;
          const int h = gcol >> 6, d = gcol & 63;
          if (mode == 1) ((unsigned short*)Cv)[(((size_t)(b * 16 + h)) * 2048 + s) * 64 + d] = bv;
          else           ((unsigned short*)Cv)[(((size_t)(b * 16 + h)) * 64 + d) * 2048 + s] = bv;
        }
      }
    }
  }
}

__global__ __launch_bounds__(256) void gemm_qkv(
    const unsigned short* __restrict__ xb,
    const unsigned short* __restrict__ wb,
    unsigned short* __restrict__ q_s,
    unsigned short* __restrict__ k_s,
    unsigned short* __restrict__ vt_s) {
  const unsigned short* W = wb + (size_t)blockIdx.z * 1048576;
  void* o; int mode;
  if (blockIdx.z == 0)      { o = q_s;  mode = 1; }
  else if (blockIdx.z == 1) { o = k_s;  mode = 1; }
  else                      { o = vt_s; mode = 2; }
  gemm_body<128>(xb, W, o, mode);
}

__global__ __launch_bounds__(256) void gemm_out(
    const unsigned short* __restrict__ a_s,
    const unsigned short* __restrict__ wb,
    float* __restrict__ out) {
  gemm_body<64>(a_s, wb + (size_t)3 * 1048576, out, 0);
}

// ---------- flash attention (causal, LDS-free, 1 wave = 32 q rows) ----------
// Q,K: (b,h,s,64) bf16 ; Vt: (b,h,64,s) bf16 ; O: (b,s,1024) bf16
// grid: 2048 blocks x 64 threads. block = one 32-row q-tile j of one bh;
// longest tiles dispatched first (j = 63 - blk/32). No LDS, no barriers:
// K/V fragments stream global->reg (L2-resident), K double-buffered.
// Swapped QK^T via mfma_f32_32x32x16_bf16: S^T[key][q], q = lane&31 lane-local.
// 32x32 C/D: col=lane&31, row=(reg&3)+8*(reg>>2)+4*(lane>>5)  [m74/m101]
// A-operand: row=lane&31, k=(lane>>5)*8+j ; B: k=(lane>>5)*8+j, col=lane&31.
// P->PV B-frag redistribution: T12 cvt_pk + v_permlane32_swap (2 swaps / 16 keys).

__global__ __launch_bounds__(64) void attn_fwd(
    const unsigned short* __restrict__ Q,
    const unsigned short* __restrict__ K,
    const unsigned short* __restrict__ Vt,
    unsigned short* __restrict__ O) {
  const int lane = threadIdx.x & 63;
  const int q31  = lane & 31;
  const int hi   = lane >> 5;
  const int blk  = blockIdx.x;
  const int jj   = blk >> 5;          // 0..63 (descending workload)
  const int bh   = blk & 31;          // same-bh blocks land on one XCD (%8)
  const int j    = 63 - jj;           // q-tile index (32 rows)
  const int nt   = (j + 2) >> 1;      // number of 64-key rounds
  const int b    = bh >> 4, h = bh & 15;
  const int qv   = j * 32 + q31;      // this lane's q row

  const unsigned short* Qb = Q  + (size_t)bh * 2048 * 64;
  const unsigned short* Kb = K  + (size_t)bh * 2048 * 64;
  const unsigned short* Vb = Vt + (size_t)bh * 64 * 2048;
  const float SC = 0.125f * 1.4426950408889634f;  // scale * log2(e)

  // Q B-frag: Q[qv][d = ds*16 + hi*8 + jx], prescaled by SC
  bf16x8 qf[4];
#pragma unroll
  for (int ds = 0; ds < 4; ++ds) {
    bf16x8 tq = ld8(Qb + (size_t)qv * 64 + ds * 16 + hi * 8);
#pragma unroll
    for (int jx = 0; jx < 8; ++jx) tq[jx] = (__bf16)((float)tq[jx] * SC);
    qf[ds] = tq;
  }

  f32x16 oacc[2] = {};                // dt = 0,1 (d tiles of 32)
  float m = -INFINITY;
  float l = 0.f;                      // per-lane partial; reduced in epilogue

  const unsigned short* kp  = Kb + (size_t)q31 * 64 + hi * 8;
  const unsigned short* vp0 = Vb + (size_t)q31 * 2048 + hi * 8;
  const unsigned short* vp1 = vp0 + (size_t)32 * 2048;

  bf16x8 kA[8], kB[8], vf[8];

  auto loadK = [&](bf16x8 (&kd)[8], int t) {
#pragma unroll
    for (int kt2 = 0; kt2 < 2; ++kt2)
#pragma unroll
      for (int ds = 0; ds < 4; ++ds)
        kd[kt2 * 4 + ds] = ld8(kp + t * 4096 + kt2 * 2048 + ds * 16);
  };
  auto loadV = [&](int t) {
#pragma unroll
    for (int ks = 0; ks < 4; ++ks) {
      vf[ks]     = ld8(vp0 + t * 64 + ks * 16);
      vf[4 + ks] = ld8(vp1 + t * 64 + ks * 16);
    }
  };

  auto round = [&](int t, bf16x8 (&kc)[8], bf16x8 (&kn)[8]) {
    loadV(t);   // consumed after softmax -> latency hidden under QK+softmax

    // QK^T: S^T[key][q], 2 key-tiles of 32
    f32x16 sv[2];
    __builtin_amdgcn_s_setprio(1);
#pragma unroll
    for (int kt2 = 0; kt2 < 2; ++kt2) {
      f32x16 a = {};
#pragma unroll
      for (int ds = 0; ds < 4; ++ds)
        a = __builtin_amdgcn_mfma_f32_32x32x16_bf16(kc[kt2 * 4 + ds], qf[ds], a, 0, 0, 0);
      sv[kt2] = a;
    }
    __builtin_amdgcn_s_setprio(0);

    if (t + 1 < nt) loadK(kn, t + 1);  // prefetch next K under softmax+PV

    // causal mask (last round only) + lane-local max
    const bool lastt = (t == nt - 1);
    float tmax = -INFINITY;
#pragma unroll
    for (int kt2 = 0; kt2 < 2; ++kt2)
#pragma unroll
      for (int r = 0; r < 16; ++r) {
        float v = sv[kt2][r];
        if (lastt) {
          const int key = t * 64 + kt2 * 32 + (r & 3) + 8 * (r >> 2) + 4 * hi;
          if (key > qv) v = -INFINITY;
        }
        sv[kt2][r] = v;
        tmax = fmaxf(tmax, v);
      }

    // defer-max (T13); m stays row-uniform (rmax reduced over the hi-pair)
    if (!__all(tmax <= m + 8.f)) {
      float rmax = fmaxf(tmax, __shfl_xor(tmax, 32));
      const float mn   = fmaxf(m, rmax);
      const float corr = exp2f(m - mn);
      l *= corr;
#pragma unroll
      for (int dt = 0; dt < 2; ++dt)
#pragma unroll
        for (int r = 0; r < 16; ++r) oacc[dt][r] *= corr;
      m = mn;
    }

    // P = exp2(S - m) in place; per-lane partial l
    float ps = 0.f;
#pragma unroll
    for (int kt2 = 0; kt2 < 2; ++kt2)
#pragma unroll
      for (int r = 0; r < 16; ++r) {
        const float p = exp2f(sv[kt2][r] - m);
        sv[kt2][r] = p;
        ps += p;
      }
    l += ps;

    // pack P into PV B-frags: per 16-key slice ks, B-elems = key 16ks+8hi+jx.
    // S-acc owns keys (r&3)+8*(r>>2)+4hi; cvt_pk own pairs, permlane32_swap
    // exchanges cross-half packs (a' = w0, b' = w2).
    unsigned int pw[4][4];
#pragma unroll
    for (int ks = 0; ks < 4; ++ks) {
      const int kt2 = ks >> 1, R = (ks & 1) * 8;
      unsigned int a0 = cvtpk(sv[kt2][R + 0], sv[kt2][R + 1]);
      unsigned int b0 = cvtpk(sv[kt2][R + 4], sv[kt2][R + 5]);
      unsigned int a1 = cvtpk(sv[kt2][R + 2], sv[kt2][R + 3]);
      unsigned int b1 = cvtpk(sv[kt2][R + 6], sv[kt2][R + 7]);
      asm("v_permlane32_swap_b32 %0, %1" : "+v"(a0), "+v"(b0));
      asm("v_permlane32_swap_b32 %0, %1" : "+v"(a1), "+v"(b1));
      pw[ks][0] = a0; pw[ks][1] = a1; pw[ks][2] = b0; pw[ks][3] = b1;
    }

    // PV: O^T[d][q] += Vt[d][key] * P^T[key][q]
    __builtin_amdgcn_s_setprio(1);
#pragma unroll
    for (int dt = 0; dt < 2; ++dt)
#pragma unroll
      for (int ks = 0; ks < 4; ++ks) {
        u32x4 t4 = {pw[ks][0], pw[ks][1], pw[ks][2], pw[ks][3]};
        bf16x8 pb = __builtin_bit_cast(bf16x8, t4);
        oacc[dt] = __builtin_amdgcn_mfma_f32_32x32x16_bf16(vf[dt * 4 + ks], pb, oacc[dt], 0, 0, 0);
      }
    __builtin_amdgcn_s_setprio(0);
  };

  loadK(kA, 0);
  int t = 0;
  while (true) {
    round(t, kA, kB); if (++t == nt) break;
    round(t, kB, kA); if (++t == nt) break;
  }

  // epilogue: l total = lane + its hi-pair (same q)
  l += __shfl_xor(l, 32);
  const float inv = 1.f / l;
  const size_t obase = ((size_t)(b * 2048 + qv)) * 1024 + h * 64;
#pragma unroll
  for (int dt = 0; dt < 2; ++dt)
#pragma unroll
    for (int r4 = 0; r4 < 4; ++r4) {
      u16x4 pk;   // regs r4*4+e -> d = dt*32 + 8*r4 + 4*hi + e
#pragma unroll
      for (int e = 0; e < 4; ++e) pk[e] = f2bf(oacc[dt][r4 * 4 + e] * inv);
      *reinterpret_cast<u16x4*>(&O[obase + dt * 32 + r4 * 8 + hi * 4]) = pk;
    }
}

// ---------- launch ----------

extern "C" void kernel_launch(void* const* d_in, const int* in_sizes, int n_in,
                              void* d_out, int out_size, void* d_ws, size_t ws_size,
                              hipStream_t stream) {
  const float* x  = (const float*)d_in[0];
  const float* Wq = (const float*)d_in[1];
  const float* Wk = (const float*)d_in[2];
  const float* Wv = (const float*)d_in[3];
  const float* Wo = (const float*)d_in[4];
  float* out = (float*)d_out;

  char* ws = (char*)d_ws;
  const size_t MiB = 1024 * 1024;
  unsigned short* x_bf = (unsigned short*)(ws);              // 8 MiB (aliased by a_s)
  unsigned short* a_s  = (unsigned short*)(ws);              // 8 MiB bf16 attn out
  unsigned short* w_bf = (unsigned short*)(ws + 8  * MiB);   // 4 x 2 MiB
  unsigned short* q_s  = (unsigned short*)(ws + 16 * MiB);   // 8 MiB
  unsigned short* k_s  = (unsigned short*)(ws + 24 * MiB);   // 8 MiB
  unsigned short* vt_s = (unsigned short*)(ws + 32 * MiB);   // 8 MiB

  cvt_inputs<<<2048, dim3(256), 0, stream>>>(x, Wq, Wk, Wv, Wo, x_bf, w_bf);
  gemm_qkv<<<dim3(8, 32, 3), dim3(256), 0, stream>>>(x_bf, w_bf, q_s, k_s, vt_s);
  attn_fwd<<<2048, dim3(64), 0, stream>>>(q_s, k_s, vt_s, a_s);
  gemm_out<<<dim3(8, 64, 1), dim3(256), 0, stream>>>(a_s, w_bf, out);
}